// Round 4
// baseline (3372.915 us; speedup 1.0000x reference)
//
#include <hip/hip_runtime.h>
#include <cstddef>

#define B_ 64
#define T_ 32
#define S_ 128
#define IN_ 1024
#define H_ 1024

typedef __bf16 bf16x8 __attribute__((ext_vector_type(8)));
typedef float f32x4 __attribute__((ext_vector_type(4)));

__device__ __forceinline__ float sigmoidf_(float x) { return 1.0f / (1.0f + expf(-x)); }

__device__ __forceinline__ ushort f2bf(float x) {
    unsigned u = __builtin_bit_cast(unsigned, x);
    unsigned r = (u + 0x7fffu + ((u >> 16) & 1u)) >> 16;
    return (ushort)r;
}
__device__ __forceinline__ float bf2f(ushort h) {
    unsigned u = ((unsigned)h) << 16;
    return __builtin_bit_cast(float, u);
}

// async global->LDS, 16B per lane; lds dest must be wave-uniform (HW adds lane*16).
__device__ __forceinline__ void gll16(const ushort* g, ushort* l) {
    __builtin_amdgcn_global_load_lds(
        (const __attribute__((address_space(1))) void*)g,
        (__attribute__((address_space(3))) void*)l,
        16, 0, 0);
}

// ---------------- big-GEMM (preamble only): C = A @ B^T, split-bf16 planes ----------
template<int FM, int FN, bool ALO, bool BLO>
__global__ __launch_bounds__(256) void gemm_bf(
    const ushort* __restrict__ Ah_g, const ushort* __restrict__ Al_g, long lda,
    const ushort* __restrict__ Bh_g, const ushort* __restrict__ Bl_g, long ldb,
    int K, int M, int N,
    float* __restrict__ Cf, ushort* __restrict__ Cb,
    const float* __restrict__ bias)
{
    constexpr int NSA = 4 * FM;
    constexpr int NSB = 4 * FN;
    constexpr int OAL = NSA;
    constexpr int OBH = NSA * (ALO ? 2 : 1);
    constexpr int OBL = OBH + NSB;
    constexpr int NST = OBH + NSB * (BLO ? 2 : 1);
    __shared__ ushort lds[NST * 512];

    const int tid = threadIdx.x;
    const int lane = tid & 63, wv = tid >> 6;
    const int wm = wv >> 1, wn = wv & 1;
    const int m0 = blockIdx.y * (FM * 32), n0 = blockIdx.x * (FN * 32);
    const int lr = lane & 15, lc = lane >> 4;

    f32x4 acc[FM][FN];
#pragma unroll
    for (int i = 0; i < FM; ++i)
#pragma unroll
        for (int j = 0; j < FN; ++j) acc[i][j] = (f32x4){0.f, 0.f, 0.f, 0.f};

    for (int k0 = 0; k0 < K; k0 += 64) {
#pragma unroll
        for (int q = 0; q < NST / 4; ++q) {
            const int si = wv * (NST / 4) + q;
            const ushort* P; long ld; int row0; int st;
            if (si < OBH) {
                if (ALO && si >= NSA) { P = Al_g; st = si - NSA; }
                else                  { P = Ah_g; st = si; }
                ld = lda; row0 = m0;
            } else {
                const int sj = si - OBH;
                if (BLO && sj >= NSB) { P = Bl_g; st = sj - NSB; }
                else                  { P = Bh_g; st = sj; }
                ld = ldb; row0 = n0;
            }
            const int row = ((st >> 1) << 4) + lr;
            const int kc = ((st & 1) << 5) + (lc << 3);
            gll16(P + (size_t)(row0 + row) * ld + k0 + kc, &lds[si * 512]);
        }
        __syncthreads();
#pragma unroll
        for (int ks = 0; ks < 2; ++ks) {
            bf16x8 ah[FM], al[FM], bh[FN], bl[FN];
#pragma unroll
            for (int i = 0; i < FM; ++i) {
                const int st = (wm * FM + i) * 2 + ks;
                ah[i] = *(const bf16x8*)&lds[st * 512 + lane * 8];
                if (ALO) al[i] = *(const bf16x8*)&lds[(OAL + st) * 512 + lane * 8];
            }
#pragma unroll
            for (int j = 0; j < FN; ++j) {
                const int st = (wn * FN + j) * 2 + ks;
                bh[j] = *(const bf16x8*)&lds[(OBH + st) * 512 + lane * 8];
                if (BLO) bl[j] = *(const bf16x8*)&lds[(OBL + st) * 512 + lane * 8];
            }
#pragma unroll
            for (int i = 0; i < FM; ++i)
#pragma unroll
                for (int j = 0; j < FN; ++j) {
                    acc[i][j] = __builtin_amdgcn_mfma_f32_16x16x32_bf16(ah[i], bh[j], acc[i][j], 0, 0, 0);
                    if (BLO) acc[i][j] = __builtin_amdgcn_mfma_f32_16x16x32_bf16(ah[i], bl[j], acc[i][j], 0, 0, 0);
                    if (ALO) acc[i][j] = __builtin_amdgcn_mfma_f32_16x16x32_bf16(al[i], bh[j], acc[i][j], 0, 0, 0);
                }
        }
        __syncthreads();
    }

    const int fr = lane & 15, fc = lane >> 4;
    if (Cb) {
#pragma unroll
        for (int i = 0; i < FM; ++i)
#pragma unroll
            for (int j = 0; j < FN; ++j) {
                const int mb = m0 + wm * FM * 16 + i * 16 + fc * 4;
                const int nb = n0 + wn * FN * 16 + j * 16 + fr;
#pragma unroll
                for (int r = 0; r < 4; ++r)
                    Cb[(size_t)(mb + r) * N + nb] = f2bf(acc[i][j][r]);
            }
    } else {
#pragma unroll
        for (int i = 0; i < FM; ++i)
#pragma unroll
            for (int j = 0; j < FN; ++j) {
                const int mb = m0 + wm * FM * 16 + i * 16 + fc * 4;
                const int nb = n0 + wn * FN * 16 + j * 16 + fr;
                const float bv = bias ? bias[nb] : 0.f;
#pragma unroll
                for (int r = 0; r < 4; ++r)
                    Cf[(size_t)(mb + r) * N + nb] = acc[i][j][r] + bv;
            }
    }
}

// ---------------- per-step kernels ----------------

// K1: gates = h @ W_hh^T (cols jc..jc+15 of each of the 4 gates) + xW_t, then LSTM cell.
// 64 blocks; wave wv computes gate wv (64 batches x 16 cols, K=1024, 3-term).
__global__ __launch_bounds__(256) void gates_lstm(
    const ushort* __restrict__ hc_h, const ushort* __restrict__ hc_l,
    const ushort* __restrict__ Whh_h, const ushort* __restrict__ Whh_l,
    const float* __restrict__ xWt,
    float* __restrict__ c_buf, ushort* __restrict__ hy_h, ushort* __restrict__ hy_l)
{
    __shared__ alignas(16) ushort lds[32 * 512];  // 32 KB; reused as float[4096] in epilogue
    const int jc = blockIdx.x * 16;
    const int tid = threadIdx.x, lane = tid & 63, wv = tid >> 6;
    const int lr = lane & 15, lc = lane >> 4;

    f32x4 acc[4];
#pragma unroll
    for (int i = 0; i < 4; ++i) acc[i] = (f32x4){0.f, 0.f, 0.f, 0.f};

    for (int k0 = 0; k0 < 1024; k0 += 64) {
#pragma unroll
        for (int q = 0; q < 8; ++q) {
            const int si = wv * 8 + q;  // 0-7 Ah, 8-15 Al, 16-23 Bh, 24-31 Bl
            const int st = si & 7;
            const ushort* P;
            size_t rowoff;
            if (si < 16) {
                P = (si < 8) ? hc_h : hc_l;
                rowoff = (size_t)(((st >> 1) << 4) + lr) * 1024;
            } else {
                P = (si < 24) ? Whh_h : Whh_l;
                const int gate = st >> 1;
                rowoff = (size_t)(gate * 1024 + jc + lr) * 1024;
            }
            const int kc = ((st & 1) << 5) + (lc << 3);
            gll16(P + rowoff + k0 + kc, &lds[si * 512]);
        }
        __syncthreads();
#pragma unroll
        for (int ks = 0; ks < 2; ++ks) {
            bf16x8 bh = *(const bf16x8*)&lds[(16 + wv * 2 + ks) * 512 + lane * 8];
            bf16x8 bl = *(const bf16x8*)&lds[(24 + wv * 2 + ks) * 512 + lane * 8];
#pragma unroll
            for (int i = 0; i < 4; ++i) {
                bf16x8 ah = *(const bf16x8*)&lds[(i * 2 + ks) * 512 + lane * 8];
                bf16x8 al = *(const bf16x8*)&lds[(8 + i * 2 + ks) * 512 + lane * 8];
                acc[i] = __builtin_amdgcn_mfma_f32_16x16x32_bf16(ah, bh, acc[i], 0, 0, 0);
                acc[i] = __builtin_amdgcn_mfma_f32_16x16x32_bf16(ah, bl, acc[i], 0, 0, 0);
                acc[i] = __builtin_amdgcn_mfma_f32_16x16x32_bf16(al, bh, acc[i], 0, 0, 0);
            }
        }
        __syncthreads();
    }

    // stash gates in LDS: gl[gate][batch][col]
    float* gl = (float*)lds;
    const int fr = lane & 15, fc = lane >> 4;
#pragma unroll
    for (int i = 0; i < 4; ++i)
#pragma unroll
        for (int r = 0; r < 4; ++r)
            gl[wv * 1024 + (i * 16 + fc * 4 + r) * 16 + fr] = acc[i][r];
    __syncthreads();

#pragma unroll
    for (int e = 0; e < 4; ++e) {
        const int p = tid + e * 256;       // 0..1023
        const int b = p >> 4, c = p & 15;
        const float* xw = xWt + (size_t)b * T_ * 4096;
        const float gi = gl[b * 16 + c]          + xw[jc + c];
        const float gf = gl[1024 + b * 16 + c]   + xw[1024 + jc + c];
        const float gg = gl[2048 + b * 16 + c]   + xw[2048 + jc + c];
        const float go = gl[3072 + b * 16 + c]   + xw[3072 + jc + c];
        const int idx = b * 1024 + jc + c;
        const float cn = sigmoidf_(gf) * c_buf[idx] + sigmoidf_(gi) * tanhf(gg);
        c_buf[idx] = cn;
        const float h = sigmoidf_(go) * tanhf(cn);
        const ushort hh = f2bf(h);
        hy_h[idx] = hh;
        hy_l[idx] = f2bf(h - bf2f(hh));
    }
}

// Core for the 16-col skinny GEMMs: C[64 x 16] = A[64 x K] @ Brows[16 x K]^T, 3-term.
// Wave wv owns batches wv*16..+15; returns its 16x16 fragment.
__device__ __forceinline__ f32x4 ngemm_core(
    const ushort* __restrict__ Ahg, const ushort* __restrict__ Alg, long lda,
    const ushort* __restrict__ Bhg, const ushort* __restrict__ Blg, long ldb,
    int K, ushort* lds)
{
    const int tid = threadIdx.x;
    const int lane = tid & 63, wv = tid >> 6;
    const int lr = lane & 15, lc = lane >> 4;
    f32x4 acc = (f32x4){0.f, 0.f, 0.f, 0.f};
    for (int k0 = 0; k0 < K; k0 += 64) {
#pragma unroll
        for (int q = 0; q < 5; ++q) {
            const int si = wv * 5 + q;  // 0-7 Ah, 8-15 Al, 16-17 Bh, 18-19 Bl
            const ushort* P;
            size_t rowoff;
            int st;
            if (si < 16) {
                st = si & 7;
                P = (si < 8) ? Ahg : Alg;
                rowoff = (size_t)(((st >> 1) << 4) + lr) * lda;
            } else {
                st = (si - 16) & 1;
                P = (si < 18) ? Bhg : Blg;
                rowoff = (size_t)lr * ldb;
            }
            const int kc = ((st & 1) << 5) + (lc << 3);
            gll16(P + rowoff + k0 + kc, &lds[si * 512]);
        }
        __syncthreads();
#pragma unroll
        for (int ks = 0; ks < 2; ++ks) {
            bf16x8 ah = *(const bf16x8*)&lds[(wv * 2 + ks) * 512 + lane * 8];
            bf16x8 al = *(const bf16x8*)&lds[(8 + wv * 2 + ks) * 512 + lane * 8];
            bf16x8 bh = *(const bf16x8*)&lds[(16 + ks) * 512 + lane * 8];
            bf16x8 bl = *(const bf16x8*)&lds[(18 + ks) * 512 + lane * 8];
            acc = __builtin_amdgcn_mfma_f32_16x16x32_bf16(ah, bh, acc, 0, 0, 0);
            acc = __builtin_amdgcn_mfma_f32_16x16x32_bf16(ah, bl, acc, 0, 0, 0);
            acc = __builtin_amdgcn_mfma_f32_16x16x32_bf16(al, bh, acc, 0, 0, 0);
        }
        __syncthreads();
    }
    return acc;
}

// K2: inp = hy @ W_in^T. 64 blocks x 16 cols. Writes inp fp32 + A_cat[:,1024+..] planes.
__global__ __launch_bounds__(256) void inp_gemm(
    const ushort* __restrict__ hy_h, const ushort* __restrict__ hy_l,
    const ushort* __restrict__ Win_h, const ushort* __restrict__ Win_l,
    float* __restrict__ inp_f, ushort* __restrict__ Ac_h, ushort* __restrict__ Ac_l)
{
    __shared__ alignas(16) ushort lds[20 * 512];
    const int nc = blockIdx.x * 16;
    f32x4 acc = ngemm_core(hy_h, hy_l, 1024,
                           Win_h + (size_t)nc * 1024, Win_l + (size_t)nc * 1024, 1024,
                           1024, lds);
    const int lane = threadIdx.x & 63, wv = threadIdx.x >> 6;
    const int fr = lane & 15, fc = lane >> 4;
#pragma unroll
    for (int r = 0; r < 4; ++r) {
        const int b = wv * 16 + fc * 4 + r;
        const int c = nc + fr;
        const float v = acc[r];
        inp_f[b * 1024 + c] = v;
        const ushort h = f2bf(v);
        Ac_h[(size_t)b * 2048 + 1024 + c] = h;
        Ac_l[(size_t)b * 2048 + 1024 + c] = f2bf(v - bf2f(h));
    }
}

// K4: h_tilde = tanh(A_cat @ W_out^T). 64 blocks x 16 cols. Writes out + h planes.
__global__ __launch_bounds__(256) void out_gemm(
    const ushort* __restrict__ Ac_h, const ushort* __restrict__ Ac_l,
    const ushort* __restrict__ Wout_h, const ushort* __restrict__ Wout_l,
    float* __restrict__ outp, ushort* __restrict__ hc_h, ushort* __restrict__ hc_l)
{
    __shared__ alignas(16) ushort lds[20 * 512];
    const int nc = blockIdx.x * 16;
    f32x4 acc = ngemm_core(Ac_h, Ac_l, 2048,
                           Wout_h + (size_t)nc * 2048, Wout_l + (size_t)nc * 2048, 2048,
                           2048, lds);
    const int lane = threadIdx.x & 63, wv = threadIdx.x >> 6;
    const int fr = lane & 15, fc = lane >> 4;
#pragma unroll
    for (int r = 0; r < 4; ++r) {
        const int b = wv * 16 + fc * 4 + r;
        const int c = nc + fr;
        const float v = tanhf(acc[r]);
        outp[(size_t)b * T_ * 1024 + c] = v;
        const int idx = b * 1024 + c;
        const ushort hh = f2bf(v);
        hc_h[idx] = hh;
        hc_l[idx] = f2bf(v - bf2f(hh));
    }
}

// K3: attention. One block per batch; reads inp fp32; writes wctx planes.
__global__ __launch_bounds__(512) void attn_kernel(
    const ushort* __restrict__ dc_all, const float* __restrict__ inp_f,
    ushort* __restrict__ Ah, ushort* __restrict__ Al, const float* __restrict__ mask)
{
    const int b = blockIdx.x;
    const int tid = threadIdx.x;
    const int lane = tid & 63;
    const int wid = tid >> 6;

    __shared__ alignas(16) float sinp[IN_];
    __shared__ float sc[S_];

    sinp[tid] = inp_f[(size_t)b * IN_ + tid];
    sinp[tid + 512] = inp_f[(size_t)b * IN_ + 512 + tid];
    __syncthreads();

    const ushort* dc = dc_all + (size_t)b * S_ * IN_;
    for (int s = wid; s < S_; s += 8) {
        const ushort* row = dc + (size_t)s * IN_;
        float sum = 0.f;
#pragma unroll
        for (int it = 0; it < 2; ++it) {
            const int e = it * 512 + lane * 8;
            const uint4 v = *(const uint4*)(row + e);
            const float4 w0 = *(const float4*)&sinp[e];
            const float4 w1 = *(const float4*)&sinp[e + 4];
            sum += bf2f(v.x & 0xffff) * w0.x + bf2f(v.x >> 16) * w0.y
                 + bf2f(v.y & 0xffff) * w0.z + bf2f(v.y >> 16) * w0.w
                 + bf2f(v.z & 0xffff) * w1.x + bf2f(v.z >> 16) * w1.y
                 + bf2f(v.w & 0xffff) * w1.z + bf2f(v.w >> 16) * w1.w;
        }
#pragma unroll
        for (int off = 32; off > 0; off >>= 1) sum += __shfl_xor(sum, off);
        if (lane == 0)
            sc[s] = sum - (1.0f - mask[(size_t)b * S_ + s]) * 100000.0f;
    }
    __syncthreads();

    if (tid < 64) {
        float v0 = sc[tid], v1 = sc[tid + 64];
        float mx = fmaxf(v0, v1);
#pragma unroll
        for (int off = 32; off > 0; off >>= 1) mx = fmaxf(mx, __shfl_xor(mx, off));
        float e0 = expf(v0 - mx), e1 = expf(v1 - mx);
        float ssum = e0 + e1;
#pragma unroll
        for (int off = 32; off > 0; off >>= 1) ssum += __shfl_xor(ssum, off);
        const float inv = 1.0f / ssum;
        sc[tid] = e0 * inv;
        sc[tid + 64] = e1 * inv;
    }
    __syncthreads();

    float ax = 0.f, ay = 0.f;
#pragma unroll 4
    for (int s = 0; s < S_; ++s) {
        const float a = sc[s];
        const unsigned v = *(const unsigned*)(dc + (size_t)s * IN_ + 2 * tid);
        ax += a * bf2f(v & 0xffff);
        ay += a * bf2f(v >> 16);
    }
    const ushort hx = f2bf(ax), hy2 = f2bf(ay);
    Ah[(size_t)b * 2048 + 2 * tid] = hx;
    Ah[(size_t)b * 2048 + 2 * tid + 1] = hy2;
    Al[(size_t)b * 2048 + 2 * tid] = f2bf(ax - bf2f(hx));
    Al[(size_t)b * 2048 + 2 * tid + 1] = f2bf(ay - bf2f(hy2));
}

// ---------------- conversion / misc ----------------
__global__ __launch_bounds__(256) void cvt2_k(
    const float* __restrict__ in, ushort* __restrict__ hi, ushort* __restrict__ lo, int n4)
{
    const int i = blockIdx.x * 256 + threadIdx.x;
    if (i >= n4) return;
    const float4 v = ((const float4*)in)[i];
    ushort4 h, l;
    h.x = f2bf(v.x); l.x = f2bf(v.x - bf2f(h.x));
    h.y = f2bf(v.y); l.y = f2bf(v.y - bf2f(h.y));
    h.z = f2bf(v.z); l.z = f2bf(v.z - bf2f(h.z));
    h.w = f2bf(v.w); l.w = f2bf(v.w - bf2f(h.w));
    ((ushort4*)hi)[i] = h;
    ((ushort4*)lo)[i] = l;
}

__global__ __launch_bounds__(256) void cvt1_k(
    const float* __restrict__ in, ushort* __restrict__ hi, int n4)
{
    const int i = blockIdx.x * 256 + threadIdx.x;
    if (i >= n4) return;
    const float4 v = ((const float4*)in)[i];
    ushort4 h;
    h.x = f2bf(v.x); h.y = f2bf(v.y); h.z = f2bf(v.z); h.w = f2bf(v.w);
    ((ushort4*)hi)[i] = h;
}

__global__ __launch_bounds__(256) void add_bias_k(
    const float* __restrict__ a, const float* __restrict__ b, float* __restrict__ o, int n)
{
    const int i = blockIdx.x * 256 + threadIdx.x;
    if (i < n) o[i] = a[i] + b[i];
}

__global__ __launch_bounds__(256) void finalize_k(
    const float* __restrict__ out_full, const float* __restrict__ c_buf,
    float* __restrict__ hT, float* __restrict__ cT)
{
    const int idx = blockIdx.x * 256 + threadIdx.x;  // < B*H
    const int b = idx >> 10, j = idx & 1023;
    hT[idx] = out_full[(size_t)b * T_ * H_ + (size_t)(T_ - 1) * H_ + j];
    cT[idx] = c_buf[idx];
}

extern "C" void kernel_launch(void* const* d_in, const int* in_sizes, int n_in,
                              void* d_out, int out_size, void* d_ws, size_t ws_size,
                              hipStream_t stream) {
    const float* target = (const float*)d_in[0];
    const float* h0     = (const float*)d_in[1];
    const float* c0     = (const float*)d_in[2];
    const float* ctx    = (const float*)d_in[3];
    const float* mask   = (const float*)d_in[4];
    const float* W_ih   = (const float*)d_in[5];
    const float* b_ih   = (const float*)d_in[6];
    const float* W_hh   = (const float*)d_in[7];
    const float* b_hh   = (const float*)d_in[8];
    const float* W_in   = (const float*)d_in[9];
    const float* W_ctx  = (const float*)d_in[10];
    const float* W_out  = (const float*)d_in[11];

    float* out = (float*)d_out;                    // (B,T,H)
    float* hT  = out + (size_t)B_ * T_ * H_;
    float* cT  = hT + (size_t)B_ * H_;

    // ---- workspace layout (persistent then transient union) ----
    ushort* dc_b   = (ushort*)d_ws;                  // dense_ctx bf16: 8,388,608
    float*  xW     = (float*)(dc_b + 8388608);       // 8,388,608 f32
    ushort* Whh_h  = (ushort*)(xW + 8388608);        // 4,194,304
    ushort* Whh_l  = Whh_h + 4194304;
    ushort* Win_h  = Whh_l + 4194304;                // 1,048,576
    ushort* Win_l  = Win_h + 1048576;
    ushort* Wout_h = Win_l + 1048576;                // 2,097,152
    ushort* Wout_l = Wout_h + 2097152;
    float*  bias_sum = (float*)(Wout_l + 2097152);   // 4096
    char*   trans  = (char*)(bias_sum + 4096);
    // phase A (pre-loop):
    ushort* ctx_h  = (ushort*)trans;                 // 16,777,216
    ushort* tgt_h  = ctx_h + 16777216;               // 2,097,152
    ushort* tgt_l  = tgt_h + 2097152;
    ushort* Wih_h  = tgt_l + 2097152;                // 4,194,304
    ushort* Wih_l  = Wih_h + 4194304;
    ushort* Wctx_h = Wih_l + 4194304;                // 2,097,152
    ushort* Wctx_l = Wctx_h + 2097152;
    // phase B (loop; aliases phase A):
    float*  c_buf  = (float*)trans;                  // 65536
    float*  inp_f  = c_buf + 65536;                  // 65536
    ushort* hy_h   = (ushort*)(inp_f + 65536);       // 65536 each
    ushort* hy_l   = hy_h + 65536;
    ushort* hc_h   = hy_l + 65536;
    ushort* hc_l   = hc_h + 65536;
    ushort* Ac_h   = hc_l + 65536;                   // 131072
    ushort* Ac_l   = Ac_h + 131072;

    // ---- pre-conversions ----
    add_bias_k<<<16, 256, 0, stream>>>(b_ih, b_hh, bias_sum, 4 * H_);
    cvt1_k<<<16384, 256, 0, stream>>>(ctx, ctx_h, 4194304);
    cvt2_k<<<2048, 256, 0, stream>>>(target, tgt_h, tgt_l, 524288);
    cvt2_k<<<4096, 256, 0, stream>>>(W_ih, Wih_h, Wih_l, 1048576);
    cvt2_k<<<4096, 256, 0, stream>>>(W_hh, Whh_h, Whh_l, 1048576);
    cvt2_k<<<1024, 256, 0, stream>>>(W_in, Win_h, Win_l, 262144);
    cvt2_k<<<2048, 256, 0, stream>>>(W_ctx, Wctx_h, Wctx_l, 524288);
    cvt2_k<<<2048, 256, 0, stream>>>(W_out, Wout_h, Wout_l, 524288);

    // dense_ctx (bf16 out) = ctx @ W_ctx^T    M=8192 N=1024 K=2048  (A 2-term)
    gemm_bf<4, 4, false, true><<<dim3(8, 64, 1), 256, 0, stream>>>(
        ctx_h, nullptr, 2 * IN_, Wctx_h, Wctx_l, 2 * IN_,
        2 * IN_, B_ * S_, IN_, nullptr, dc_b, nullptr);

    // xW = target @ W_ih^T + bias             M=2048 N=4096 K=1024
    gemm_bf<4, 4, true, true><<<dim3(32, 16, 1), 256, 0, stream>>>(
        tgt_h, tgt_l, IN_, Wih_h, Wih_l, IN_,
        IN_, B_ * T_, 4 * H_, xW, nullptr, bias_sum);

    // loop-state init (after big GEMMs: aliased region)
    cvt2_k<<<64, 256, 0, stream>>>(h0, hc_h, hc_l, 16384);
    hipMemcpyAsync(c_buf, c0, sizeof(float) * B_ * H_, hipMemcpyDeviceToDevice, stream);

    for (int t = 0; t < T_; ++t) {
        gates_lstm<<<64, 256, 0, stream>>>(hc_h, hc_l, Whh_h, Whh_l,
                                           xW + (size_t)t * 4096, c_buf, hy_h, hy_l);
        inp_gemm<<<64, 256, 0, stream>>>(hy_h, hy_l, Win_h, Win_l, inp_f, Ac_h, Ac_l);
        attn_kernel<<<B_, 512, 0, stream>>>(dc_b, inp_f, Ac_h, Ac_l, mask);
        out_gemm<<<64, 256, 0, stream>>>(Ac_h, Ac_l, Wout_h, Wout_l,
                                         out + (size_t)t * H_, hc_h, hc_l);
    }

    finalize_k<<<256, 256, 0, stream>>>(out, c_buf, hT, cT);
}

// Round 6
// 2091.718 us; speedup vs baseline: 1.6125x; 1.6125x over previous
//
#include <hip/hip_runtime.h>
#include <cstddef>

#define B_ 64
#define T_ 32
#define S_ 128
#define IN_ 1024
#define H_ 1024

typedef __bf16 bf16x8 __attribute__((ext_vector_type(8)));
typedef float f32x4 __attribute__((ext_vector_type(4)));

__device__ __forceinline__ float sigmoidf_(float x) { return 1.0f / (1.0f + expf(-x)); }

__device__ __forceinline__ ushort f2bf(float x) {
    unsigned u = __builtin_bit_cast(unsigned, x);
    unsigned r = (u + 0x7fffu + ((u >> 16) & 1u)) >> 16;
    return (ushort)r;
}
__device__ __forceinline__ float bf2f(ushort h) {
    unsigned u = ((unsigned)h) << 16;
    return __builtin_bit_cast(float, u);
}

// async global->LDS, 16B per lane; lds dest wave-uniform (HW adds lane*16).
__device__ __forceinline__ void gll16(const ushort* g, ushort* l) {
    __builtin_amdgcn_global_load_lds(
        (const __attribute__((address_space(1))) void*)g,
        (__attribute__((address_space(3))) void*)l,
        16, 0, 0);
}

// ---------------- big-GEMM (preamble): C = A @ B^T, split-bf16 planes ----------
// out modes: Cf!=null -> fp32 (+bias); else Cbl!=null -> hi/lo planes; else Cbh bf16.
template<int FM, int FN, bool ALO, bool BLO>
__global__ __launch_bounds__(256) void gemm_bf(
    const ushort* __restrict__ Ah_g, const ushort* __restrict__ Al_g, long lda,
    const ushort* __restrict__ Bh_g, const ushort* __restrict__ Bl_g, long ldb,
    int K, int M, int N,
    float* __restrict__ Cf, ushort* __restrict__ Cbh, ushort* __restrict__ Cbl,
    const float* __restrict__ bias)
{
    constexpr int NSA = 4 * FM;
    constexpr int NSB = 4 * FN;
    constexpr int OAL = NSA;
    constexpr int OBH = NSA * (ALO ? 2 : 1);
    constexpr int OBL = OBH + NSB;
    constexpr int NST = OBH + NSB * (BLO ? 2 : 1);
    __shared__ ushort lds[NST * 512];

    const int tid = threadIdx.x;
    const int lane = tid & 63, wv = tid >> 6;
    const int wm = wv >> 1, wn = wv & 1;
    const int m0 = blockIdx.y * (FM * 32), n0 = blockIdx.x * (FN * 32);
    const int lr = lane & 15, lc = lane >> 4;

    f32x4 acc[FM][FN];
#pragma unroll
    for (int i = 0; i < FM; ++i)
#pragma unroll
        for (int j = 0; j < FN; ++j) acc[i][j] = (f32x4){0.f, 0.f, 0.f, 0.f};

    for (int k0 = 0; k0 < K; k0 += 64) {
#pragma unroll
        for (int q = 0; q < NST / 4; ++q) {
            const int si = wv * (NST / 4) + q;
            const ushort* P; long ld; int row0; int st;
            if (si < OBH) {
                if (ALO && si >= NSA) { P = Al_g; st = si - NSA; }
                else                  { P = Ah_g; st = si; }
                ld = lda; row0 = m0;
            } else {
                const int sj = si - OBH;
                if (BLO && sj >= NSB) { P = Bl_g; st = sj - NSB; }
                else                  { P = Bh_g; st = sj; }
                ld = ldb; row0 = n0;
            }
            const int row = ((st >> 1) << 4) + lr;
            const int kc = ((st & 1) << 5) + (lc << 3);
            gll16(P + (size_t)(row0 + row) * ld + k0 + kc, &lds[si * 512]);
        }
        __syncthreads();
#pragma unroll
        for (int ks = 0; ks < 2; ++ks) {
            bf16x8 ah[FM], al[FM], bh[FN], bl[FN];
#pragma unroll
            for (int i = 0; i < FM; ++i) {
                const int st = (wm * FM + i) * 2 + ks;
                ah[i] = *(const bf16x8*)&lds[st * 512 + lane * 8];
                if (ALO) al[i] = *(const bf16x8*)&lds[(OAL + st) * 512 + lane * 8];
            }
#pragma unroll
            for (int j = 0; j < FN; ++j) {
                const int st = (wn * FN + j) * 2 + ks;
                bh[j] = *(const bf16x8*)&lds[(OBH + st) * 512 + lane * 8];
                if (BLO) bl[j] = *(const bf16x8*)&lds[(OBL + st) * 512 + lane * 8];
            }
#pragma unroll
            for (int i = 0; i < FM; ++i)
#pragma unroll
                for (int j = 0; j < FN; ++j) {
                    acc[i][j] = __builtin_amdgcn_mfma_f32_16x16x32_bf16(ah[i], bh[j], acc[i][j], 0, 0, 0);
                    if (BLO) acc[i][j] = __builtin_amdgcn_mfma_f32_16x16x32_bf16(ah[i], bl[j], acc[i][j], 0, 0, 0);
                    if (ALO) acc[i][j] = __builtin_amdgcn_mfma_f32_16x16x32_bf16(al[i], bh[j], acc[i][j], 0, 0, 0);
                }
        }
        __syncthreads();
    }

    const int fr = lane & 15, fc = lane >> 4;
#pragma unroll
    for (int i = 0; i < FM; ++i)
#pragma unroll
        for (int j = 0; j < FN; ++j) {
            const int mb = m0 + wm * FM * 16 + i * 16 + fc * 4;
            const int nb = n0 + wn * FN * 16 + j * 16 + fr;
            const float bv = bias ? bias[nb] : 0.f;
#pragma unroll
            for (int r = 0; r < 4; ++r) {
                const float v = acc[i][j][r] + bv;
                const size_t o = (size_t)(mb + r) * N + nb;
                if (Cf) Cf[o] = v;
                else if (Cbl) { const ushort hh = f2bf(v); Cbh[o] = hh; Cbl[o] = f2bf(v - bf2f(hh)); }
                else Cbh[o] = f2bf(v);
            }
        }
}

// ---------------- per-step kernels ----------------

// K1: gates (4 gates x 16 cols) for 16 batches, full K=1024, 3-term; fused LSTM cell.
// grid (64 colgrp, 4 batchgrp); wave g computes gate g.
__global__ __launch_bounds__(256) void gates_cell(
    const ushort* __restrict__ hc_h, const ushort* __restrict__ hc_l,
    const ushort* __restrict__ Whh_h, const ushort* __restrict__ Whh_l,
    const float* __restrict__ xWt,
    float* __restrict__ c_buf, ushort* __restrict__ hy_h, ushort* __restrict__ hy_l)
{
    __shared__ ushort lds[20 * 512];   // 20 KB staging
    __shared__ float gl[1024];         // 4 KB gate swap
    const int jc = blockIdx.x;
    const int mb = blockIdx.y;
    const int tid = threadIdx.x, lane = tid & 63, wv = tid >> 6;
    const int lr = lane & 15, lc = lane >> 4;

    f32x4 acc = (f32x4){0.f, 0.f, 0.f, 0.f};

    for (int k0 = 0; k0 < 1024; k0 += 64) {
#pragma unroll
        for (int q = 0; q < 5; ++q) {
            const int si = wv * 5 + q;
            const ushort* P; size_t rowoff; int ks;
            if (si < 4) {
                P = (si < 2) ? hc_h : hc_l;
                ks = si & 1;
                rowoff = (size_t)(mb * 16 + lr) * 1024;
            } else {
                const int sj = si - 4;
                P = (sj < 8) ? Whh_h : Whh_l;
                const int g = (sj & 7) >> 1;
                ks = sj & 1;
                rowoff = (size_t)(g * 1024 + jc * 16 + lr) * 1024;
            }
            gll16(P + rowoff + k0 + ks * 32 + lc * 8, &lds[si * 512]);
        }
        __syncthreads();
#pragma unroll
        for (int ks = 0; ks < 2; ++ks) {
            bf16x8 ah = *(const bf16x8*)&lds[ks * 512 + lane * 8];
            bf16x8 al = *(const bf16x8*)&lds[(2 + ks) * 512 + lane * 8];
            bf16x8 bh = *(const bf16x8*)&lds[(4 + wv * 2 + ks) * 512 + lane * 8];
            bf16x8 bl = *(const bf16x8*)&lds[(12 + wv * 2 + ks) * 512 + lane * 8];
            acc = __builtin_amdgcn_mfma_f32_16x16x32_bf16(ah, bh, acc, 0, 0, 0);
            acc = __builtin_amdgcn_mfma_f32_16x16x32_bf16(ah, bl, acc, 0, 0, 0);
            acc = __builtin_amdgcn_mfma_f32_16x16x32_bf16(al, bh, acc, 0, 0, 0);
        }
        __syncthreads();
    }

    const int fr = lane & 15, fc = lane >> 4;
#pragma unroll
    for (int r = 0; r < 4; ++r)
        gl[wv * 256 + (fc * 4 + r) * 16 + fr] = acc[r];
    __syncthreads();

    const int bl_ = tid >> 4, cl = tid & 15;
    const int b = mb * 16 + bl_, col = jc * 16 + cl;
    const float* xw = xWt + (size_t)b * T_ * 4096;
    const float gi = gl[bl_ * 16 + cl]        + xw[col];
    const float gf = gl[256 + bl_ * 16 + cl]  + xw[1024 + col];
    const float gg = gl[512 + bl_ * 16 + cl]  + xw[2048 + col];
    const float go = gl[768 + bl_ * 16 + cl]  + xw[3072 + col];
    const int idx = b * 1024 + col;
    const float cn = sigmoidf_(gf) * c_buf[idx] + sigmoidf_(gi) * tanhf(gg);
    c_buf[idx] = cn;
    const float h = sigmoidf_(go) * tanhf(cn);
    const ushort hh = f2bf(h);
    hy_h[idx] = hh;
    hy_l[idx] = f2bf(h - bf2f(hh));
}

// K2: attention. scores = E[b] @ hy[b] - neg; softmax; wctx = a @ dc[b] -> planes.
__global__ __launch_bounds__(512) void attn_k(
    const float* __restrict__ E, const ushort* __restrict__ dc_all,
    const ushort* __restrict__ hy_h, const ushort* __restrict__ hy_l,
    ushort* __restrict__ wc_h, ushort* __restrict__ wc_l,
    const float* __restrict__ mask)
{
    const int b = blockIdx.x;
    const int tid = threadIdx.x;
    const int lane = tid & 63;
    const int wid = tid >> 6;

    __shared__ alignas(16) float sinp[IN_];
    __shared__ float sc[S_];

    sinp[tid]       = bf2f(hy_h[b * 1024 + tid])       + bf2f(hy_l[b * 1024 + tid]);
    sinp[tid + 512] = bf2f(hy_h[b * 1024 + 512 + tid]) + bf2f(hy_l[b * 1024 + 512 + tid]);
    __syncthreads();

    const float4* s4 = (const float4*)sinp;
    for (int s = wid; s < S_; s += 8) {
        const float4* row = (const float4*)(E + ((size_t)b * S_ + s) * 1024);
        float sum = 0.f;
#pragma unroll
        for (int it = 0; it < 4; ++it) {
            const float4 v = row[lane + it * 64];
            const float4 w = s4[lane + it * 64];
            sum += v.x * w.x + v.y * w.y + v.z * w.z + v.w * w.w;
        }
#pragma unroll
        for (int off = 32; off > 0; off >>= 1) sum += __shfl_xor(sum, off);
        if (lane == 0)
            sc[s] = sum - (1.0f - mask[(size_t)b * S_ + s]) * 100000.0f;
    }
    __syncthreads();

    if (tid < 64) {
        float v0 = sc[tid], v1 = sc[tid + 64];
        float mx = fmaxf(v0, v1);
#pragma unroll
        for (int off = 32; off > 0; off >>= 1) mx = fmaxf(mx, __shfl_xor(mx, off));
        float e0 = expf(v0 - mx), e1 = expf(v1 - mx);
        float ssum = e0 + e1;
#pragma unroll
        for (int off = 32; off > 0; off >>= 1) ssum += __shfl_xor(ssum, off);
        const float inv = 1.0f / ssum;
        sc[tid] = e0 * inv;
        sc[tid + 64] = e1 * inv;
    }
    __syncthreads();

    const ushort* dc = dc_all + (size_t)b * S_ * IN_;
    float ax = 0.f, ay = 0.f;
#pragma unroll 4
    for (int s = 0; s < S_; ++s) {
        const float a = sc[s];
        const unsigned v = *(const unsigned*)(dc + (size_t)s * IN_ + 2 * tid);
        ax += a * bf2f(v & 0xffff);
        ay += a * bf2f(v >> 16);
    }
    const ushort hx = f2bf(ax), hy2 = f2bf(ay);
    wc_h[(size_t)b * 1024 + 2 * tid]     = hx;
    wc_h[(size_t)b * 1024 + 2 * tid + 1] = hy2;
    wc_l[(size_t)b * 1024 + 2 * tid]     = f2bf(ax - bf2f(hx));
    wc_l[(size_t)b * 1024 + 2 * tid + 1] = f2bf(ay - bf2f(hy2));
}

// K3: h = tanh(wctx @ Wo1^T + hy @ Woi^T). grid (64 colgrp, 4 batchgrp).
// Waves split K (wave-private double-buffered staging, counted vmcnt, no barriers
// in the K-loop), then LDS reduce across waves.
__global__ __launch_bounds__(256) void out_h(
    const ushort* __restrict__ wc_h, const ushort* __restrict__ wc_l,
    const ushort* __restrict__ hy_h, const ushort* __restrict__ hy_l,
    const ushort* __restrict__ Wo1_h, const ushort* __restrict__ Wo1_l,
    const ushort* __restrict__ Woi_h, const ushort* __restrict__ Woi_l,
    float* __restrict__ outp, ushort* __restrict__ hc_h, ushort* __restrict__ hc_l)
{
    __shared__ ushort lds[4][2][4096];   // 64 KB: per wave, 2 bufs x 8 subtiles(1KB)
    __shared__ float red[1024];          // 4 KB cross-wave reduce
    const int nc = blockIdx.x;
    const int mb = blockIdx.y;
    const int tid = threadIdx.x, lane = tid & 63, wv = tid >> 6;
    const int lr = lane & 15, lc = lane >> 4;
    const int kb = wv * 256;

    const size_t arow = (size_t)(mb * 16 + lr) * 1024;
    const size_t brow = (size_t)(nc * 16 + lr) * 1024;

    // iter it (0..7): half = it>>2 (0: wc@Wo1, 1: hy@Woi), k = kb + (it&3)*64
#define OH_ISSUE(IT, BUF)                                                        \
    {                                                                            \
        const ushort* Ah_ = ((IT) < 4) ? wc_h : hy_h;                            \
        const ushort* Al_ = ((IT) < 4) ? wc_l : hy_l;                            \
        const ushort* Bh_ = ((IT) < 4) ? Wo1_h : Woi_h;                          \
        const ushort* Bl_ = ((IT) < 4) ? Wo1_l : Woi_l;                          \
        const int k0_ = kb + ((IT) & 3) * 64 + lc * 8;                           \
        ushort* dst_ = &lds[wv][BUF][0];                                         \
        gll16(Ah_ + arow + k0_,      dst_);                                      \
        gll16(Ah_ + arow + k0_ + 32, dst_ + 512);                                \
        gll16(Al_ + arow + k0_,      dst_ + 1024);                               \
        gll16(Al_ + arow + k0_ + 32, dst_ + 1536);                               \
        gll16(Bh_ + brow + k0_,      dst_ + 2048);                               \
        gll16(Bh_ + brow + k0_ + 32, dst_ + 2560);                               \
        gll16(Bl_ + brow + k0_,      dst_ + 3072);                               \
        gll16(Bl_ + brow + k0_ + 32, dst_ + 3584);                               \
    }

    f32x4 acc = (f32x4){0.f, 0.f, 0.f, 0.f};
    OH_ISSUE(0, 0)
#pragma unroll
    for (int it = 0; it < 8; ++it) {
        if (it < 7) {
            OH_ISSUE(it + 1, (it + 1) & 1)
            asm volatile("s_waitcnt vmcnt(8)" ::: "memory");  // wait iter it's 8 loads
        } else {
            asm volatile("s_waitcnt vmcnt(0)" ::: "memory");
        }
        __builtin_amdgcn_sched_barrier(0);
        const ushort* W = &lds[wv][it & 1][0];
#pragma unroll
        for (int ks = 0; ks < 2; ++ks) {
            bf16x8 ah = *(const bf16x8*)&W[ks * 512 + lane * 8];
            bf16x8 al = *(const bf16x8*)&W[(2 + ks) * 512 + lane * 8];
            bf16x8 bh = *(const bf16x8*)&W[(4 + ks) * 512 + lane * 8];
            bf16x8 bl = *(const bf16x8*)&W[(6 + ks) * 512 + lane * 8];
            acc = __builtin_amdgcn_mfma_f32_16x16x32_bf16(ah, bh, acc, 0, 0, 0);
            acc = __builtin_amdgcn_mfma_f32_16x16x32_bf16(ah, bl, acc, 0, 0, 0);
            acc = __builtin_amdgcn_mfma_f32_16x16x32_bf16(al, bh, acc, 0, 0, 0);
        }
    }
#undef OH_ISSUE

    const int fc = lane >> 4, fr = lane & 15;
#pragma unroll
    for (int r = 0; r < 4; ++r)
        red[wv * 256 + (fc * 4 + r) * 16 + fr] = acc[r];
    __syncthreads();

    const int bl_ = tid >> 4, cl = tid & 15;
    float v = red[bl_ * 16 + cl] + red[256 + bl_ * 16 + cl]
            + red[512 + bl_ * 16 + cl] + red[768 + bl_ * 16 + cl];
    v = tanhf(v);
    const int b = mb * 16 + bl_, col = nc * 16 + cl;
    outp[(size_t)b * T_ * 1024 + col] = v;
    const int idx = b * 1024 + col;
    const ushort hh = f2bf(v);
    hc_h[idx] = hh;
    hc_l[idx] = f2bf(v - bf2f(hh));
}

// ---------------- conversion / misc ----------------
__global__ __launch_bounds__(256) void cvt2_k(
    const float* __restrict__ in, ushort* __restrict__ hi, ushort* __restrict__ lo, int n4)
{
    const int i = blockIdx.x * 256 + threadIdx.x;
    if (i >= n4) return;
    const float4 v = ((const float4*)in)[i];
    ushort4 h, l;
    h.x = f2bf(v.x); l.x = f2bf(v.x - bf2f(h.x));
    h.y = f2bf(v.y); l.y = f2bf(v.y - bf2f(h.y));
    h.z = f2bf(v.z); l.z = f2bf(v.z - bf2f(h.z));
    h.w = f2bf(v.w); l.w = f2bf(v.w - bf2f(h.w));
    ((ushort4*)hi)[i] = h;
    ((ushort4*)lo)[i] = l;
}

__global__ __launch_bounds__(256) void cvt1_k(
    const float* __restrict__ in, ushort* __restrict__ hi, int n4)
{
    const int i = blockIdx.x * 256 + threadIdx.x;
    if (i >= n4) return;
    const float4 v = ((const float4*)in)[i];
    ushort4 h;
    h.x = f2bf(v.x); h.y = f2bf(v.y); h.z = f2bf(v.z); h.w = f2bf(v.w);
    ((ushort4*)hi)[i] = h;
}

// strided cvt2: row r has rowlen4 float4s read from in + r*instride4 (float4 units)
__global__ __launch_bounds__(256) void cvt2s_k(
    const float* __restrict__ in, long instride4, int rowlen4,
    ushort* __restrict__ hi, ushort* __restrict__ lo, int n4)
{
    const int i = blockIdx.x * 256 + threadIdx.x;
    if (i >= n4) return;
    const int r = i / rowlen4, c = i - r * rowlen4;
    const float4 v = ((const float4*)in)[(size_t)r * instride4 + c];
    ushort4 h, l;
    h.x = f2bf(v.x); l.x = f2bf(v.x - bf2f(h.x));
    h.y = f2bf(v.y); l.y = f2bf(v.y - bf2f(h.y));
    h.z = f2bf(v.z); l.z = f2bf(v.z - bf2f(h.z));
    h.w = f2bf(v.w); l.w = f2bf(v.w - bf2f(h.w));
    ((ushort4*)hi)[i] = h;
    ((ushort4*)lo)[i] = l;
}

__global__ void transpose_k(const float* __restrict__ in, float* __restrict__ out)
{
    __shared__ float tile[32][33];
    const int bx = blockIdx.x * 32, by = blockIdx.y * 32;
    const int tx = threadIdx.x, ty = threadIdx.y;   // (32,8)
#pragma unroll
    for (int i = 0; i < 32; i += 8)
        tile[ty + i][tx] = in[(size_t)(by + ty + i) * 1024 + bx + tx];
    __syncthreads();
#pragma unroll
    for (int i = 0; i < 32; i += 8)
        out[(size_t)(bx + ty + i) * 1024 + by + tx] = tile[tx][ty + i];
}

__global__ __launch_bounds__(256) void add_bias_k(
    const float* __restrict__ a, const float* __restrict__ b, float* __restrict__ o, int n)
{
    const int i = blockIdx.x * 256 + threadIdx.x;
    if (i < n) o[i] = a[i] + b[i];
}

__global__ __launch_bounds__(256) void finalize_k(
    const float* __restrict__ out_full, const float* __restrict__ c_buf,
    float* __restrict__ hT, float* __restrict__ cT)
{
    const int idx = blockIdx.x * 256 + threadIdx.x;
    const int b = idx >> 10, j = idx & 1023;
    hT[idx] = out_full[(size_t)b * T_ * H_ + (size_t)(T_ - 1) * H_ + j];
    cT[idx] = c_buf[idx];
}

extern "C" void kernel_launch(void* const* d_in, const int* in_sizes, int n_in,
                              void* d_out, int out_size, void* d_ws, size_t ws_size,
                              hipStream_t stream) {
    const float* target = (const float*)d_in[0];
    const float* h0     = (const float*)d_in[1];
    const float* c0     = (const float*)d_in[2];
    const float* ctx    = (const float*)d_in[3];
    const float* mask   = (const float*)d_in[4];
    const float* W_ih   = (const float*)d_in[5];
    const float* b_ih   = (const float*)d_in[6];
    const float* W_hh   = (const float*)d_in[7];
    const float* b_hh   = (const float*)d_in[8];
    const float* W_in   = (const float*)d_in[9];
    const float* W_ctx  = (const float*)d_in[10];
    const float* W_out  = (const float*)d_in[11];

    float* out = (float*)d_out;
    float* hT  = out + (size_t)B_ * T_ * H_;
    float* cT  = hT + (size_t)B_ * H_;

    // ---- workspace layout ----
    char* p = (char*)d_ws;
    ushort* dc_b  = (ushort*)p;            p += 8388608ull * 2;    // 16.78 MB
    float*  E     = (float*)p;             p += 8388608ull * 4;    // 33.55 MB (first: ctx_h)
    float*  xW    = (float*)p;             p += 8388608ull * 4;    // 33.55 MB
    ushort* Whh_h = (ushort*)p;            p += 4194304ull * 2;
    ushort* Whh_l = (ushort*)p;            p += 4194304ull * 2;
    ushort* Wo1_h = (ushort*)p;            p += 1048576ull * 2;
    ushort* Wo1_l = (ushort*)p;            p += 1048576ull * 2;
    ushort* Woi_h = (ushort*)p;            p += 1048576ull * 2;
    ushort* Woi_l = (ushort*)p;            p += 1048576ull * 2;
    float*  bias_sum = (float*)p;          p += 4096ull * 4;
    float*  c_buf = (float*)p;             p += 65536ull * 4;
    ushort* hy_h  = (ushort*)p;            p += 65536ull * 2;
    ushort* hy_l  = (ushort*)p;            p += 65536ull * 2;
    ushort* hc_h  = (ushort*)p;            p += 65536ull * 2;
    ushort* hc_l  = (ushort*)p;            p += 65536ull * 2;
    ushort* wc_h  = (ushort*)p;            p += 65536ull * 2;
    ushort* wc_l  = (ushort*)p;            p += 65536ull * 2;
    ushort* TR    = (ushort*)p;                                     // transient
    ushort* ctx_h = (ushort*)E;            // ctx bf16 lives in E's slot pre-E
    // TR phase A: W_ctx planes
    ushort* Wctx_h = TR;
    ushort* Wctx_l = TR + 2097152;
    // TR phase B: W_in^T + W_out2 + Woi staging
    float*  WinT_f = (float*)TR;                       // 4.19 MB
    ushort* WinT_h = TR + 2097152;
    ushort* WinT_l = TR + 3145728;
    ushort* Wo2_h  = TR + 4194304;
    ushort* Wo2_l  = TR + 5242880;
    float*  Woi_f  = (float*)(TR + 6291456);           // 4.19 MB
    // TR phase C: target + W_ih planes
    ushort* tgt_h  = TR;
    ushort* tgt_l  = TR + 2097152;
    ushort* Wih_h  = TR + 4194304;
    ushort* Wih_l  = TR + 8388608;

    // ---- preamble ----
    add_bias_k<<<16, 256, 0, stream>>>(b_ih, b_hh, bias_sum, 4 * H_);
    cvt2_k<<<4096, 256, 0, stream>>>(W_hh, Whh_h, Whh_l, 1048576);
    cvt2s_k<<<1024, 256, 0, stream>>>(W_out, 512, 256, Wo1_h, Wo1_l, 262144);

    // dense_ctx (bf16) = ctx @ W_ctx^T
    cvt1_k<<<16384, 256, 0, stream>>>(ctx, ctx_h, 4194304);
    cvt2_k<<<2048, 256, 0, stream>>>(W_ctx, Wctx_h, Wctx_l, 524288);
    gemm_bf<4, 4, false, true><<<dim3(8, 64), 256, 0, stream>>>(
        ctx_h, nullptr, 2048, Wctx_h, Wctx_l, 2048,
        2048, 8192, 1024, nullptr, dc_b, nullptr, nullptr);

    // W_in^T, W_oi = W_out2 @ W_in, E = dense_ctx @ W_in
    transpose_k<<<dim3(32, 32), dim3(32, 8), 0, stream>>>(W_in, WinT_f);
    cvt2_k<<<1024, 256, 0, stream>>>(WinT_f, WinT_h, WinT_l, 262144);
    cvt2s_k<<<1024, 256, 0, stream>>>(W_out + 1024, 512, 256, Wo2_h, Wo2_l, 262144);
    gemm_bf<4, 4, true, true><<<dim3(8, 8), 256, 0, stream>>>(
        Wo2_h, Wo2_l, 1024, WinT_h, WinT_l, 1024,
        1024, 1024, 1024, Woi_f, nullptr, nullptr, nullptr);
    cvt2_k<<<1024, 256, 0, stream>>>(Woi_f, Woi_h, Woi_l, 262144);
    gemm_bf<4, 4, false, true><<<dim3(8, 64), 256, 0, stream>>>(
        dc_b, nullptr, 1024, WinT_h, WinT_l, 1024,
        1024, 8192, 1024, E, nullptr, nullptr, nullptr);

    // xW = target @ W_ih^T + bias
    cvt2_k<<<2048, 256, 0, stream>>>(target, tgt_h, tgt_l, 524288);
    cvt2_k<<<4096, 256, 0, stream>>>(W_ih, Wih_h, Wih_l, 1048576);
    gemm_bf<4, 4, true, true><<<dim3(32, 16), 256, 0, stream>>>(
        tgt_h, tgt_l, 1024, Wih_h, Wih_l, 1024,
        1024, 2048, 4096, xW, nullptr, nullptr, bias_sum);

    // loop state
    cvt2_k<<<64, 256, 0, stream>>>(h0, hc_h, hc_l, 16384);
    hipMemcpyAsync(c_buf, c0, sizeof(float) * B_ * H_, hipMemcpyDeviceToDevice, stream);

    for (int t = 0; t < T_; ++t) {
        gates_cell<<<dim3(64, 4), 256, 0, stream>>>(
            hc_h, hc_l, Whh_h, Whh_l, xW + (size_t)t * 4096, c_buf, hy_h, hy_l);
        attn_k<<<64, 512, 0, stream>>>(E, dc_b, hy_h, hy_l, wc_h, wc_l, mask);
        out_h<<<dim3(64, 4), 256, 0, stream>>>(
            wc_h, wc_l, hy_h, hy_l, Wo1_h, Wo1_l, Woi_h, Woi_l,
            out + (size_t)t * H_, hc_h, hc_l);
    }

    finalize_k<<<256, 256, 0, stream>>>(out, c_buf, hT, cT);
}

// Round 7
// 1477.549 us; speedup vs baseline: 2.2828x; 1.4157x over previous
//
#include <hip/hip_runtime.h>
#include <cstddef>

#define B_ 64
#define T_ 32
#define S_ 128
#define IN_ 1024
#define H_ 1024

typedef __bf16 bf16x8 __attribute__((ext_vector_type(8)));
typedef float f32x4 __attribute__((ext_vector_type(4)));

__device__ __forceinline__ float sigmoidf_(float x) { return 1.0f / (1.0f + expf(-x)); }

__device__ __forceinline__ ushort f2bf(float x) {
    unsigned u = __builtin_bit_cast(unsigned, x);
    unsigned r = (u + 0x7fffu + ((u >> 16) & 1u)) >> 16;
    return (ushort)r;
}
__device__ __forceinline__ float bf2f(ushort h) {
    unsigned u = ((unsigned)h) << 16;
    return __builtin_bit_cast(float, u);
}

// async global->LDS, 16B per lane; lds dest wave-uniform (HW adds lane*16).
__device__ __forceinline__ void gll16(const ushort* g, ushort* l) {
    __builtin_amdgcn_global_load_lds(
        (const __attribute__((address_space(1))) void*)g,
        (__attribute__((address_space(3))) void*)l,
        16, 0, 0);
}

// ---------------- big-GEMM (preamble): C = A @ B^T, split-bf16 planes ----------
// Optional blockIdx.z batching via element strides Az/Bz/Cz.
// out modes: Cf!=null -> fp32 (+bias); else Cbl!=null -> hi/lo planes; else Cbh bf16.
template<int FM, int FN, bool ALO, bool BLO>
__global__ __launch_bounds__(256) void gemm_bf(
    const ushort* __restrict__ Ah_g, const ushort* __restrict__ Al_g, long lda,
    const ushort* __restrict__ Bh_g, const ushort* __restrict__ Bl_g, long ldb,
    int K, int N,
    float* __restrict__ Cf, ushort* __restrict__ Cbh, ushort* __restrict__ Cbl,
    const float* __restrict__ bias,
    long Az, long Bz, long Cz)
{
    constexpr int NSA = 4 * FM;
    constexpr int NSB = 4 * FN;
    constexpr int OAL = NSA;
    constexpr int OBH = NSA * (ALO ? 2 : 1);
    constexpr int OBL = OBH + NSB;
    constexpr int NST = OBH + NSB * (BLO ? 2 : 1);
    __shared__ ushort lds[NST * 512];

    const long z = blockIdx.z;
    Ah_g += z * Az; if (ALO) Al_g += z * Az;
    Bh_g += z * Bz; if (BLO) Bl_g += z * Bz;
    if (Cf) Cf += z * Cz;
    if (Cbh) Cbh += z * Cz;
    if (Cbl) Cbl += z * Cz;

    const int tid = threadIdx.x;
    const int lane = tid & 63, wv = tid >> 6;
    const int wm = wv >> 1, wn = wv & 1;
    const int m0 = blockIdx.y * (FM * 32), n0 = blockIdx.x * (FN * 32);
    const int lr = lane & 15, lc = lane >> 4;

    f32x4 acc[FM][FN];
#pragma unroll
    for (int i = 0; i < FM; ++i)
#pragma unroll
        for (int j = 0; j < FN; ++j) acc[i][j] = (f32x4){0.f, 0.f, 0.f, 0.f};

    for (int k0 = 0; k0 < K; k0 += 64) {
#pragma unroll
        for (int q = 0; q < NST / 4; ++q) {
            const int si = wv * (NST / 4) + q;
            const ushort* P; long ld; int row0; int st;
            if (si < OBH) {
                if (ALO && si >= NSA) { P = Al_g; st = si - NSA; }
                else                  { P = Ah_g; st = si; }
                ld = lda; row0 = m0;
            } else {
                const int sj = si - OBH;
                if (BLO && sj >= NSB) { P = Bl_g; st = sj - NSB; }
                else                  { P = Bh_g; st = sj; }
                ld = ldb; row0 = n0;
            }
            const int row = ((st >> 1) << 4) + lr;
            const int kc = ((st & 1) << 5) + (lc << 3);
            gll16(P + (size_t)(row0 + row) * ld + k0 + kc, &lds[si * 512]);
        }
        __syncthreads();
#pragma unroll
        for (int ks = 0; ks < 2; ++ks) {
            bf16x8 ah[FM], al[FM], bh[FN], bl[FN];
#pragma unroll
            for (int i = 0; i < FM; ++i) {
                const int st = (wm * FM + i) * 2 + ks;
                ah[i] = *(const bf16x8*)&lds[st * 512 + lane * 8];
                if (ALO) al[i] = *(const bf16x8*)&lds[(OAL + st) * 512 + lane * 8];
            }
#pragma unroll
            for (int j = 0; j < FN; ++j) {
                const int st = (wn * FN + j) * 2 + ks;
                bh[j] = *(const bf16x8*)&lds[(OBH + st) * 512 + lane * 8];
                if (BLO) bl[j] = *(const bf16x8*)&lds[(OBL + st) * 512 + lane * 8];
            }
#pragma unroll
            for (int i = 0; i < FM; ++i)
#pragma unroll
                for (int j = 0; j < FN; ++j) {
                    acc[i][j] = __builtin_amdgcn_mfma_f32_16x16x32_bf16(ah[i], bh[j], acc[i][j], 0, 0, 0);
                    if (BLO) acc[i][j] = __builtin_amdgcn_mfma_f32_16x16x32_bf16(ah[i], bl[j], acc[i][j], 0, 0, 0);
                    if (ALO) acc[i][j] = __builtin_amdgcn_mfma_f32_16x16x32_bf16(al[i], bh[j], acc[i][j], 0, 0, 0);
                }
        }
        __syncthreads();
    }

    const int fr = lane & 15, fc = lane >> 4;
#pragma unroll
    for (int i = 0; i < FM; ++i)
#pragma unroll
        for (int j = 0; j < FN; ++j) {
            const int mb = m0 + wm * FM * 16 + i * 16 + fc * 4;
            const int nb = n0 + wn * FN * 16 + j * 16 + fr;
            const float bv = bias ? bias[nb] : 0.f;
#pragma unroll
            for (int r = 0; r < 4; ++r) {
                const float v = acc[i][j][r] + bv;
                const size_t o = (size_t)(mb + r) * N + nb;
                if (Cf) Cf[o] = v;
                else if (Cbl) { const ushort hh = f2bf(v); Cbh[o] = hh; Cbl[o] = f2bf(v - bf2f(hh)); }
                else Cbh[o] = f2bf(v);
            }
        }
}

// ---------------- per-step kernels ----------------

__device__ __forceinline__ void gc_issue(
    const ushort* __restrict__ hc_h, const ushort* __restrict__ hc_l,
    const ushort* __restrict__ Whh_h, const ushort* __restrict__ Whh_l,
    int jc, int mb, int wv, int lr, int lc, int k0, ushort* dst)
{
#pragma unroll
    for (int q = 0; q < 5; ++q) {
        const int si = wv * 5 + q;
        const ushort* P; size_t rowoff; int ks;
        if (si < 4) {
            P = (si < 2) ? hc_h : hc_l;
            ks = si & 1;
            rowoff = (size_t)(mb * 16 + lr) * 1024;
        } else {
            const int sj = si - 4;
            P = (sj < 8) ? Whh_h : Whh_l;
            const int g = (sj & 7) >> 1;
            ks = sj & 1;
            rowoff = (size_t)(g * 1024 + jc * 16 + lr) * 1024;
        }
        gll16(P + rowoff + k0 + ks * 32 + lc * 8, dst + si * 512);
    }
}

// K1: gates (4 gates x 16 cols) for 16 batches, K=1024, 3-term; fused LSTM cell.
// grid (64 colgrp, 4 batchgrp); wave g = gate g. 3-buffer pipeline: raw s_barrier +
// counted vmcnt(5) -> loads stay in flight across the barrier (one barrier/iter).
__global__ __launch_bounds__(256) void gates_cell(
    const ushort* __restrict__ hc_h, const ushort* __restrict__ hc_l,
    const ushort* __restrict__ Whh_h, const ushort* __restrict__ Whh_l,
    const float* __restrict__ xWt,
    float* __restrict__ c_buf, ushort* __restrict__ hy_h, ushort* __restrict__ hy_l)
{
    __shared__ ushort lds[3][10240];   // 60 KB
    __shared__ float gl[1024];         // 4 KB
    const int jc = blockIdx.x;
    const int mb = blockIdx.y;
    const int tid = threadIdx.x, lane = tid & 63, wv = tid >> 6;
    const int lr = lane & 15, lc = lane >> 4;

    f32x4 acc = (f32x4){0.f, 0.f, 0.f, 0.f};

    gc_issue(hc_h, hc_l, Whh_h, Whh_l, jc, mb, wv, lr, lc, 0, &lds[0][0]);
#pragma unroll
    for (int it = 0; it < 16; ++it) {
        if (it < 15) {
            gc_issue(hc_h, hc_l, Whh_h, Whh_l, jc, mb, wv, lr, lc,
                     (it + 1) * 64, &lds[(it + 1) % 3][0]);
            asm volatile("s_waitcnt vmcnt(5)" ::: "memory");
        } else {
            asm volatile("s_waitcnt vmcnt(0)" ::: "memory");
        }
        __builtin_amdgcn_s_barrier();
        __builtin_amdgcn_sched_barrier(0);
        const ushort* L = &lds[it % 3][0];
#pragma unroll
        for (int ks = 0; ks < 2; ++ks) {
            bf16x8 ah = *(const bf16x8*)&L[ks * 512 + lane * 8];
            bf16x8 al = *(const bf16x8*)&L[(2 + ks) * 512 + lane * 8];
            bf16x8 bh = *(const bf16x8*)&L[(4 + wv * 2 + ks) * 512 + lane * 8];
            bf16x8 bl = *(const bf16x8*)&L[(12 + wv * 2 + ks) * 512 + lane * 8];
            acc = __builtin_amdgcn_mfma_f32_16x16x32_bf16(ah, bh, acc, 0, 0, 0);
            acc = __builtin_amdgcn_mfma_f32_16x16x32_bf16(ah, bl, acc, 0, 0, 0);
            acc = __builtin_amdgcn_mfma_f32_16x16x32_bf16(al, bh, acc, 0, 0, 0);
        }
    }

    const int fr = lane & 15, fc = lane >> 4;
#pragma unroll
    for (int r = 0; r < 4; ++r)
        gl[wv * 256 + (fc * 4 + r) * 16 + fr] = acc[r];
    __syncthreads();

    const int bl_ = tid >> 4, cl = tid & 15;
    const int b = mb * 16 + bl_, col = jc * 16 + cl;
    const float* xw = xWt + (size_t)b * T_ * 4096;
    const float gi = gl[bl_ * 16 + cl]        + xw[col];
    const float gf = gl[256 + bl_ * 16 + cl]  + xw[1024 + col];
    const float gg = gl[512 + bl_ * 16 + cl]  + xw[2048 + col];
    const float go = gl[768 + bl_ * 16 + cl]  + xw[3072 + col];
    const int idx = b * 1024 + col;
    const float cn = sigmoidf_(gf) * c_buf[idx] + sigmoidf_(gi) * tanhf(gg);
    c_buf[idx] = cn;
    const float h = sigmoidf_(go) * tanhf(cn);
    const ushort hh = f2bf(h);
    hy_h[idx] = hh;
    hy_l[idx] = f2bf(h - bf2f(hh));
}

// K2: raw scores. grid (64 b, 4 sgroup of 32). sc_raw[b,s] = E[b,s,:]·hy[b,:] - neg.
__global__ __launch_bounds__(256) void scores_k(
    const float* __restrict__ E,
    const ushort* __restrict__ hy_h, const ushort* __restrict__ hy_l,
    const float* __restrict__ mask, float* __restrict__ sc_raw)
{
    const int b = blockIdx.x, sg = blockIdx.y;
    const int tid = threadIdx.x, lane = tid & 63, wv = tid >> 6;
    __shared__ alignas(16) float sinp[IN_];
#pragma unroll
    for (int i = 0; i < 4; ++i) {
        const int j = tid + i * 256;
        sinp[j] = bf2f(hy_h[b * 1024 + j]) + bf2f(hy_l[b * 1024 + j]);
    }
    __syncthreads();
    const float4* s4 = (const float4*)sinp;
#pragma unroll
    for (int r = 0; r < 8; ++r) {
        const int s = sg * 32 + wv * 8 + r;
        const float4* row = (const float4*)(E + ((size_t)b * S_ + s) * 1024);
        float sum = 0.f;
#pragma unroll
        for (int i = 0; i < 4; ++i) {
            const float4 v = row[lane + i * 64];
            const float4 w = s4[lane + i * 64];
            sum += v.x * w.x + v.y * w.y + v.z * w.z + v.w * w.w;
        }
#pragma unroll
        for (int off = 32; off > 0; off >>= 1) sum += __shfl_xor(sum, off);
        if (lane == 0)
            sc_raw[b * S_ + s] = sum - (1.0f - mask[(size_t)b * S_ + s]) * 100000.0f;
    }
}

__device__ __forceinline__ void og_issue(
    const ushort* __restrict__ hy_h, const ushort* __restrict__ hy_l,
    const ushort* __restrict__ Woi_h, const ushort* __restrict__ Woi_l,
    size_t arow, size_t brow, int kb, int it, int lc, ushort* dst)
{
    const int k0 = kb + it * 64 + lc * 8;
    gll16(hy_h + arow + k0,       dst);
    gll16(hy_h + arow + k0 + 32,  dst + 512);
    gll16(hy_l + arow + k0,       dst + 1024);
    gll16(hy_l + arow + k0 + 32,  dst + 1536);
    gll16(Woi_h + brow + k0,      dst + 2048);
    gll16(Woi_h + brow + k0 + 32, dst + 2560);
    gll16(Woi_l + brow + k0,      dst + 3072);
    gll16(Woi_l + brow + k0 + 32, dst + 3584);
}

// K3: out = tanh( softmax(sc) @ Gt + hy @ Woi^T ). grid (64 colgrp, 4 batchgrp).
// Softmax per 16-lane group (redundant across nc, deterministic). G-part: VALU stream
// of Gt[b][c][0..127] hi/lo. MFMA part: wave-private K-split dbuf (round-6 scheme).
__global__ __launch_bounds__(256) void outg_k(
    const float* __restrict__ sc_raw,
    const ushort* __restrict__ Gt_h, const ushort* __restrict__ Gt_l,
    const ushort* __restrict__ hy_h, const ushort* __restrict__ hy_l,
    const ushort* __restrict__ Woi_h, const ushort* __restrict__ Woi_l,
    float* __restrict__ outp, ushort* __restrict__ hc_h, ushort* __restrict__ hc_l)
{
    __shared__ ushort st[4][2][4096];   // 64 KB
    __shared__ float aS[16][128];       // 8 KB
    __shared__ float red[1024];         // 4 KB
    const int nc = blockIdx.x, mb = blockIdx.y;
    const int tid = threadIdx.x, lane = tid & 63, wv = tid >> 6;
    const int lr = lane & 15, lc = lane >> 4;
    const int kb = wv * 256;
    const size_t arow = (size_t)(mb * 16 + lr) * 1024;
    const size_t brow = (size_t)(nc * 16 + lr) * 1024;

    og_issue(hy_h, hy_l, Woi_h, Woi_l, arow, brow, kb, 0, lc, &st[wv][0][0]);

    // softmax for this block's 16 batches (16 lanes per batch, in-wave)
    const int bl_ = tid >> 4, tl = tid & 15;
    const int b = mb * 16 + bl_;
    float v[8], mx = -3.4e38f;
#pragma unroll
    for (int i = 0; i < 8; ++i) {
        v[i] = sc_raw[b * S_ + tl * 8 + i];
        mx = fmaxf(mx, v[i]);
    }
#pragma unroll
    for (int off = 1; off < 16; off <<= 1) mx = fmaxf(mx, __shfl_xor(mx, off));
    float sm = 0.f;
#pragma unroll
    for (int i = 0; i < 8; ++i) { v[i] = expf(v[i] - mx); sm += v[i]; }
#pragma unroll
    for (int off = 1; off < 16; off <<= 1) sm += __shfl_xor(sm, off);
    const float inv = 1.0f / sm;
#pragma unroll
    for (int i = 0; i < 8; ++i) aS[bl_][tl * 8 + i] = v[i] * inv;
    asm volatile("s_waitcnt lgkmcnt(0)" ::: "memory");

    // G accumulation: thread (bl_, tl) -> out col nc*16+tl of batch b
    const int c = nc * 16 + tl;
    const ushort* gh = Gt_h + ((size_t)b * 1024 + c) * 128;
    const ushort* glo = Gt_l + ((size_t)b * 1024 + c) * 128;
    float accg = 0.f;
#pragma unroll
    for (int i = 0; i < 16; ++i) {
        const uint4 vh = *(const uint4*)(gh + i * 8);
        const uint4 vl = *(const uint4*)(glo + i * 8);
        const float* a = &aS[bl_][i * 8];
        accg += a[0] * (bf2f(vh.x & 0xffff) + bf2f(vl.x & 0xffff));
        accg += a[1] * (bf2f(vh.x >> 16)    + bf2f(vl.x >> 16));
        accg += a[2] * (bf2f(vh.y & 0xffff) + bf2f(vl.y & 0xffff));
        accg += a[3] * (bf2f(vh.y >> 16)    + bf2f(vl.y >> 16));
        accg += a[4] * (bf2f(vh.z & 0xffff) + bf2f(vl.z & 0xffff));
        accg += a[5] * (bf2f(vh.z >> 16)    + bf2f(vl.z >> 16));
        accg += a[6] * (bf2f(vh.w & 0xffff) + bf2f(vl.w & 0xffff));
        accg += a[7] * (bf2f(vh.w >> 16)    + bf2f(vl.w >> 16));
    }

    // MFMA part: hy @ Woi^T, wave-private K range, double-buffered
    asm volatile("s_waitcnt vmcnt(0)" ::: "memory");
    f32x4 acc = (f32x4){0.f, 0.f, 0.f, 0.f};
#pragma unroll
    for (int it = 0; it < 4; ++it) {
        if (it < 3) {
            og_issue(hy_h, hy_l, Woi_h, Woi_l, arow, brow, kb, it + 1, lc,
                     &st[wv][(it + 1) & 1][0]);
            asm volatile("s_waitcnt vmcnt(8)" ::: "memory");
        } else {
            asm volatile("s_waitcnt vmcnt(0)" ::: "memory");
        }
        __builtin_amdgcn_sched_barrier(0);
        const ushort* W = &st[wv][it & 1][0];
#pragma unroll
        for (int ks = 0; ks < 2; ++ks) {
            bf16x8 ah = *(const bf16x8*)&W[ks * 512 + lane * 8];
            bf16x8 al = *(const bf16x8*)&W[(2 + ks) * 512 + lane * 8];
            bf16x8 bh = *(const bf16x8*)&W[(4 + ks) * 512 + lane * 8];
            bf16x8 bl = *(const bf16x8*)&W[(6 + ks) * 512 + lane * 8];
            acc = __builtin_amdgcn_mfma_f32_16x16x32_bf16(ah, bh, acc, 0, 0, 0);
            acc = __builtin_amdgcn_mfma_f32_16x16x32_bf16(ah, bl, acc, 0, 0, 0);
            acc = __builtin_amdgcn_mfma_f32_16x16x32_bf16(al, bh, acc, 0, 0, 0);
        }
    }

    const int fc = lane >> 4, fr = lane & 15;
#pragma unroll
    for (int r = 0; r < 4; ++r)
        red[wv * 256 + (fc * 4 + r) * 16 + fr] = acc[r];
    __syncthreads();

    float o = accg + red[bl_ * 16 + tl] + red[256 + bl_ * 16 + tl]
            + red[512 + bl_ * 16 + tl] + red[768 + bl_ * 16 + tl];
    o = tanhf(o);
    outp[(size_t)b * T_ * 1024 + c] = o;
    const int idx = b * 1024 + c;
    const ushort hh = f2bf(o);
    hc_h[idx] = hh;
    hc_l[idx] = f2bf(o - bf2f(hh));
}

// ---------------- conversion / misc ----------------
__global__ __launch_bounds__(256) void cvt2_k(
    const float* __restrict__ in, ushort* __restrict__ hi, ushort* __restrict__ lo, int n4)
{
    const int i = blockIdx.x * 256 + threadIdx.x;
    if (i >= n4) return;
    const float4 v = ((const float4*)in)[i];
    ushort4 h, l;
    h.x = f2bf(v.x); l.x = f2bf(v.x - bf2f(h.x));
    h.y = f2bf(v.y); l.y = f2bf(v.y - bf2f(h.y));
    h.z = f2bf(v.z); l.z = f2bf(v.z - bf2f(h.z));
    h.w = f2bf(v.w); l.w = f2bf(v.w - bf2f(h.w));
    ((ushort4*)hi)[i] = h;
    ((ushort4*)lo)[i] = l;
}

__global__ __launch_bounds__(256) void cvt1_k(
    const float* __restrict__ in, ushort* __restrict__ hi, int n4)
{
    const int i = blockIdx.x * 256 + threadIdx.x;
    if (i >= n4) return;
    const float4 v = ((const float4*)in)[i];
    ushort4 h;
    h.x = f2bf(v.x); h.y = f2bf(v.y); h.z = f2bf(v.z); h.w = f2bf(v.w);
    ((ushort4*)hi)[i] = h;
}

__global__ __launch_bounds__(256) void cvt2s_k(
    const float* __restrict__ in, long instride4, int rowlen4,
    ushort* __restrict__ hi, ushort* __restrict__ lo, int n4)
{
    const int i = blockIdx.x * 256 + threadIdx.x;
    if (i >= n4) return;
    const int r = i / rowlen4, c = i - r * rowlen4;
    const float4 v = ((const float4*)in)[(size_t)r * instride4 + c];
    ushort4 h, l;
    h.x = f2bf(v.x); l.x = f2bf(v.x - bf2f(h.x));
    h.y = f2bf(v.y); l.y = f2bf(v.y - bf2f(h.y));
    h.z = f2bf(v.z); l.z = f2bf(v.z - bf2f(h.z));
    h.w = f2bf(v.w); l.w = f2bf(v.w - bf2f(h.w));
    ((ushort4*)hi)[i] = h;
    ((ushort4*)lo)[i] = l;
}

__global__ void transpose_k(const float* __restrict__ in, float* __restrict__ out)
{
    __shared__ float tile[32][33];
    const int bx = blockIdx.x * 32, by = blockIdx.y * 32;
    const int tx = threadIdx.x, ty = threadIdx.y;   // (32,8)
#pragma unroll
    for (int i = 0; i < 32; i += 8)
        tile[ty + i][tx] = in[(size_t)(by + ty + i) * 1024 + bx + tx];
    __syncthreads();
#pragma unroll
    for (int i = 0; i < 32; i += 8)
        out[(size_t)(bx + ty + i) * 1024 + by + tx] = tile[tx][ty + i];
}

__global__ __launch_bounds__(256) void add_bias_k(
    const float* __restrict__ a, const float* __restrict__ b, float* __restrict__ o, int n)
{
    const int i = blockIdx.x * 256 + threadIdx.x;
    if (i < n) o[i] = a[i] + b[i];
}

__global__ __launch_bounds__(256) void finalize_k(
    const float* __restrict__ out_full, const float* __restrict__ c_buf,
    float* __restrict__ hT, float* __restrict__ cT)
{
    const int idx = blockIdx.x * 256 + threadIdx.x;
    const int b = idx >> 10, j = idx & 1023;
    hT[idx] = out_full[(size_t)b * T_ * H_ + (size_t)(T_ - 1) * H_ + j];
    cT[idx] = c_buf[idx];
}

extern "C" void kernel_launch(void* const* d_in, const int* in_sizes, int n_in,
                              void* d_out, int out_size, void* d_ws, size_t ws_size,
                              hipStream_t stream) {
    const float* target = (const float*)d_in[0];
    const float* h0     = (const float*)d_in[1];
    const float* c0     = (const float*)d_in[2];
    const float* ctx    = (const float*)d_in[3];
    const float* mask   = (const float*)d_in[4];
    const float* W_ih   = (const float*)d_in[5];
    const float* b_ih   = (const float*)d_in[6];
    const float* W_hh   = (const float*)d_in[7];
    const float* b_hh   = (const float*)d_in[8];
    const float* W_in   = (const float*)d_in[9];
    const float* W_ctx  = (const float*)d_in[10];
    const float* W_out  = (const float*)d_in[11];

    float* out = (float*)d_out;
    float* hT  = out + (size_t)B_ * T_ * H_;
    float* cT  = hT + (size_t)B_ * H_;

    // ---- workspace layout ----
    char* p = (char*)d_ws;
    float*  E     = (float*)p;             p += 8388608ull * 4;    // 33.55 MB (hosts ctx_h first)
    float*  xW    = (float*)p;             p += 8388608ull * 4;    // 33.55 MB
    ushort* Gt_h  = (ushort*)p;            p += 8388608ull * 2;    // 16.78 MB
    ushort* Gt_l  = (ushort*)p;            p += 8388608ull * 2;    // 16.78 MB
    ushort* Whh_h = (ushort*)p;            p += 4194304ull * 2;
    ushort* Whh_l = (ushort*)p;            p += 4194304ull * 2;
    ushort* Woi_h = (ushort*)p;            p += 1048576ull * 2;
    ushort* Woi_l = (ushort*)p;            p += 1048576ull * 2;
    float*  bias_sum = (float*)p;          p += 4096ull * 4;
    float*  c_buf = (float*)p;             p += 65536ull * 4;
    ushort* hy_h  = (ushort*)p;            p += 65536ull * 2;
    ushort* hy_l  = (ushort*)p;            p += 65536ull * 2;
    ushort* hc_h  = (ushort*)p;            p += 65536ull * 2;
    ushort* hc_l  = (ushort*)p;            p += 65536ull * 2;
    float*  sc_raw = (float*)p;            p += 8192ull * 4;
    ushort* dcslot = (ushort*)p;           p += 8388608ull * 2;    // 16.78 MB (dc_b, later tgt)
    ushort* trans  = (ushort*)p;           p += 8388608ull * 2;    // 16.78 MB shared transient

    ushort* ctx_h  = (ushort*)E;           // ctx bf16 in E slot (dead before E written)
    ushort* dc_b   = dcslot;
    // transient phase A: W_ctx planes
    ushort* Wctx_h = trans;
    ushort* Wctx_l = trans + 2097152;
    // transient phase B: WinT + Wo1 + Wo2 planes + WinT_f
    ushort* WinT_h = trans;
    ushort* WinT_l = trans + 1048576;
    ushort* Wo1_h  = trans + 2097152;
    ushort* Wo1_l  = trans + 3145728;
    ushort* Wo2_h  = trans + 4194304;
    ushort* Wo2_l  = trans + 5242880;
    float*  WinT_f = (float*)(trans + 6291456);
    // transient phase C: target planes (dc slot) + W_ih planes (trans)
    ushort* tgt_h  = dcslot;
    ushort* tgt_l  = dcslot + 2097152;
    ushort* Wih_h  = trans;
    ushort* Wih_l  = trans + 4194304;

    // ---- preamble ----
    add_bias_k<<<16, 256, 0, stream>>>(b_ih, b_hh, bias_sum, 4 * H_);
    cvt2_k<<<4096, 256, 0, stream>>>(W_hh, Whh_h, Whh_l, 1048576);

    // dense_ctx (bf16) = ctx @ W_ctx^T
    cvt1_k<<<16384, 256, 0, stream>>>(ctx, ctx_h, 4194304);
    cvt2_k<<<2048, 256, 0, stream>>>(W_ctx, Wctx_h, Wctx_l, 524288);
    gemm_bf<4, 4, false, true><<<dim3(8, 64), 256, 0, stream>>>(
        ctx_h, nullptr, 2048, Wctx_h, Wctx_l, 2048,
        2048, 1024, nullptr, dc_b, nullptr, nullptr, 0, 0, 0);

    // WinT, Woi = Wo2@W_in, E = dc@W_in, Gt[b] = Wo1 @ dc[b]^T
    transpose_k<<<dim3(32, 32), dim3(32, 8), 0, stream>>>(W_in, WinT_f);
    cvt2_k<<<1024, 256, 0, stream>>>(WinT_f, WinT_h, WinT_l, 262144);
    cvt2s_k<<<1024, 256, 0, stream>>>(W_out, 512, 256, Wo1_h, Wo1_l, 262144);
    cvt2s_k<<<1024, 256, 0, stream>>>(W_out + 1024, 512, 256, Wo2_h, Wo2_l, 262144);
    gemm_bf<4, 4, true, true><<<dim3(8, 8), 256, 0, stream>>>(
        Wo2_h, Wo2_l, 1024, WinT_h, WinT_l, 1024,
        1024, 1024, nullptr, Woi_h, Woi_l, nullptr, 0, 0, 0);
    gemm_bf<4, 4, false, true><<<dim3(8, 64), 256, 0, stream>>>(
        dc_b, nullptr, 1024, WinT_h, WinT_l, 1024,
        1024, 1024, E, nullptr, nullptr, nullptr, 0, 0, 0);
    gemm_bf<4, 4, true, false><<<dim3(1, 8, 64), 256, 0, stream>>>(
        Wo1_h, Wo1_l, 1024, dc_b, nullptr, 1024,
        1024, 128, nullptr, Gt_h, Gt_l, nullptr, 0, 131072, 131072);

    // xW = target @ W_ih^T + bias (dc dead now)
    cvt2_k<<<2048, 256, 0, stream>>>(target, tgt_h, tgt_l, 524288);
    cvt2_k<<<4096, 256, 0, stream>>>(W_ih, Wih_h, Wih_l, 1048576);
    gemm_bf<4, 4, true, true><<<dim3(32, 16), 256, 0, stream>>>(
        tgt_h, tgt_l, 1024, Wih_h, Wih_l, 1024,
        1024, 4096, xW, nullptr, nullptr, bias_sum, 0, 0, 0);

    // loop state
    cvt2_k<<<64, 256, 0, stream>>>(h0, hc_h, hc_l, 16384);
    hipMemcpyAsync(c_buf, c0, sizeof(float) * B_ * H_, hipMemcpyDeviceToDevice, stream);

    for (int t = 0; t < T_; ++t) {
        gates_cell<<<dim3(64, 4), 256, 0, stream>>>(
            hc_h, hc_l, Whh_h, Whh_l, xW + (size_t)t * 4096, c_buf, hy_h, hy_l);
        scores_k<<<dim3(64, 4), 256, 0, stream>>>(E, hy_h, hy_l, mask, sc_raw);
        outg_k<<<dim3(64, 4), 256, 0, stream>>>(
            sc_raw, Gt_h, Gt_l, hy_h, hy_l, Woi_h, Woi_l,
            out + (size_t)t * H_, hc_h, hc_l);
    }

    finalize_k<<<256, 256, 0, stream>>>(out, c_buf, hT, cT);
}